// Round 13
// baseline (520.266 us; speedup 1.0000x reference)
//
#include <hip/hip_runtime.h>

// softmax(Q.V^T).V — deferred-normalization pipeline (fp16):
//   conv:  Q -> Qh fp16;  V -> Vh fp16 + VT (=Vh^T)
//   GEMM1 (MODE 1): S-tile = Qh.Vh^T; per-wave epilogue per 64-col chunk:
//       m_c = chunk row-max (16-lane shfl), P = fp16(exp(S-m_c)), s_c = row-sum.
//       TPW=2 M-tiles per block: same B (Vh) panel re-staged L2-hot, NT=32.
//   GEMM2 (MODE 2): prologue computes r2'[c][r] = exp(m_c-m_g)/denom from
//       mtab/stab (k_stats folded in); out = sum_c (P_c * r2'[c]) . VT_c^T.
// GEMM geometry (proven R9 core): 256² tile, BK=64, 8 waves (2x4), 4 phases
// x16 MFMA, counted vmcnt(6), XOR-swizzle via pre-swizzled global source,
// XCD-aware bijective block remap.

#define B_ 16
#define LQ_ 2048
#define LV_ 2048
#define DD_ 1024

typedef unsigned short u16;
typedef _Float16 f16x8 __attribute__((ext_vector_type(8)));
typedef __attribute__((ext_vector_type(4))) float f32x4;
typedef __attribute__((ext_vector_type(4))) unsigned short u16x4;

__device__ __forceinline__ u16 f2h(float x) {
  union { _Float16 h; u16 u; } c;
  c.h = (_Float16)x;
  return c.u;
}
__device__ __forceinline__ float h2f(u16 u) {
  union { _Float16 h; u16 u; } c;
  c.u = u;
  return (float)c.h;
}

__device__ __forceinline__ void gload16(const u16* g, u16* lds) {
  __builtin_amdgcn_global_load_lds(
      (const __attribute__((address_space(1))) void*)g,
      (__attribute__((address_space(3))) void*)lds, 16, 0, 0);
}

#define BARRIER() do { asm volatile("" ::: "memory"); __builtin_amdgcn_s_barrier(); asm volatile("" ::: "memory"); } while (0)
#define WAITVM(N) asm volatile("s_waitcnt vmcnt(" #N ")" ::: "memory")

// ---------------- 256x256 BK=64 GEMM, M-multi-tile ----------------
// Block computes TPW M-tiles (same N cols n0, M rows m0base..+TPW*256),
// TPS K-steps each, one flat gt loop of NT = TPW*TPS steps.
// MODE 1: A.B^T -> P=exp(S-m_chunk) fp16 + per-64-col-chunk m/s tables
// MODE 2: sum_c (A_c*r2'[c]).B_c^T -> fp32; r2' computed in prologue
template <int TPW, int TPS, int MODE>
__global__ __launch_bounds__(512, 2) void k_gemm8(
    const u16* __restrict__ A, const u16* __restrict__ B,
    u16* __restrict__ Pout, float* __restrict__ Fout,
    float* __restrict__ mtab, float* __restrict__ stab,
    int N, int lda, int ldb, size_t aBatch, size_t bBatch, size_t cBatch) {
  constexpr int NT = TPW * TPS;
  __shared__ u16 lds[65536];  // A: 2 bufs x 256x64 | B: 2 bufs x 256x64
  __shared__ u16 ldsR2[(MODE == 2) ? 8192 : 64];  // [32 K-chunks][256 rows]
  u16* ldsA = lds;
  u16* ldsB = lds + 32768;

  // XCD-aware bijective remap (nwg % 8 == 0)
  int bx, by, bz;
  {
    const int gx = gridDim.x, gy = gridDim.y;
    const int lid = blockIdx.x + gx * (blockIdx.y + gy * blockIdx.z);
    const int nwg = gx * gy * gridDim.z;
    const int q = nwg >> 3;
    const int nid = (lid & 7) * q + (lid >> 3);
    bx = nid % gx;
    const int rem = nid / gx;
    by = rem % gy;
    bz = rem / gy;
  }

  const int tid = threadIdx.x;
  const int w = tid >> 6, l = tid & 63;
  const int m0base = by * (TPW * 256);
  const int n0 = bx << 8;
  const int wr = w >> 2, wc = w & 3;  // 2(M) x 4(N) waves -> 128x64 per wave
  const int wr128 = wr * 128, wc64 = wc * 64;
  const int fr = l & 15, kx = l >> 4, fr7 = l & 7, cc = l & 15;
  const int srow = l >> 3;
  const int gsrc8 = (((l & 7) ^ ((l >> 3) & 7)) << 3);  // inverse-swizzled src granule

  const u16* Ab = A + (size_t)bz * aBatch;
  const u16* Bb = B + (size_t)bz * bBatch;

  if constexpr (MODE == 2) {
    // --- folded stats: r2'[c][r] = exp(m_c - m_g) / denom, rows m0..m0+255 ---
    if (tid < 256) {
      const int r = tid;
      const size_t base = (size_t)bz * 32 * 2048 + m0base + r;
      float mg = -3.0e38f;
#pragma unroll
      for (int c = 0; c < 32; ++c) mg = fmaxf(mg, mtab[base + (size_t)c * 2048]);
      float denom = 0.f;
#pragma unroll
      for (int c = 0; c < 32; ++c) {
        const float f = __expf(mtab[base + (size_t)c * 2048] - mg);
        denom += stab[base + (size_t)c * 2048] * f;
        ldsR2[c * 256 + r] = f2h(f);
      }
      const float inv = 1.0f / denom;
#pragma unroll
      for (int c = 0; c < 32; ++c)
        ldsR2[c * 256 + r] = f2h(h2f(ldsR2[c * 256 + r]) * inv);
    }
    __syncthreads();
  }

  // A half h covers rows {h*64..h*64+63} u {128+h*64..+63} of M-tile (tt/TPS)
#define STAGE_A(tt, h)                                                          \
  do {                                                                          \
    const int kk_ = ((tt) % TPS) * 64;                                          \
    const int ma_ = m0base + ((tt) / TPS) * 256;                                \
    u16* d0_ = ldsA + ((tt) & 1) * 16384 + ((h) * 64 + w * 8) * 64;             \
    const u16* g0_ = Ab + (size_t)(ma_ + (h) * 64 + w * 8 + srow) * lda + kk_ + gsrc8; \
    gload16(g0_, d0_);                                                          \
    gload16(g0_ + (size_t)128 * lda, d0_ + 128 * 64);                           \
  } while (0)

  // B half h covers tile rows { k*64 + h*32 .. +31 : k=0..3 } (n0 fixed)
#define STAGE_B(tt, h)                                                          \
  do {                                                                          \
    const int kk_ = ((tt) % TPS) * 64;                                          \
    const int rb_ = (w >> 2) * 64 + (h) * 32 + (w & 3) * 8;                     \
    u16* d0_ = ldsB + ((tt) & 1) * 16384 + rb_ * 64;                            \
    const u16* g0_ = Bb + (size_t)(n0 + rb_ + srow) * ldb + kk_ + gsrc8;        \
    gload16(g0_, d0_);                                                          \
    gload16(g0_ + (size_t)128 * ldb, d0_ + 8192);                               \
  } while (0)

#define RA8(MOFF)                                                                   \
  {                                                                                 \
    _Pragma("unroll") for (int m_ = 0; m_ < 4; ++m_) {                              \
      _Pragma("unroll") for (int k_ = 0; k_ < 2; ++k_) {                            \
        af[m_][k_] = *(const f16x8*)(ldsA + bufo +                                  \
            (wr128 + (MOFF) + m_ * 16 + fr) * 64 + (((kx + k_ * 4) ^ fr7) << 3));   \
        if constexpr (MODE == 2) af[m_][k_] = af[m_][k_] * r2h[(MOFF) / 16 + m_];   \
      }                                                                             \
    }                                                                               \
  }

#define RB4(NF0)                                                                    \
  {                                                                                 \
    _Pragma("unroll") for (int n_ = 0; n_ < 2; ++n_) {                              \
      _Pragma("unroll") for (int k_ = 0; k_ < 2; ++k_) {                            \
        bf[(NF0) + n_][k_] = *(const f16x8*)(ldsB + bufo +                          \
            (wc64 + ((NF0) + n_) * 16 + fr) * 64 + (((kx + k_ * 4) ^ fr7) << 3));   \
      }                                                                             \
    }                                                                               \
  }

#define MFMA8(MF0, NF0)                                                             \
  {                                                                                 \
    _Pragma("unroll") for (int m_ = 0; m_ < 4; ++m_)                                \
    _Pragma("unroll") for (int n_ = 0; n_ < 2; ++n_)                                \
    _Pragma("unroll") for (int k_ = 0; k_ < 2; ++k_)                                \
        acc[(MF0) + m_][(NF0) + n_] = __builtin_amdgcn_mfma_f32_16x16x32_f16(       \
            af[m_][k_], bf[(NF0) + n_][k_], acc[(MF0) + m_][(NF0) + n_], 0, 0, 0);  \
  }

  f32x4 acc[8][4];
#pragma unroll
  for (int i = 0; i < 8; ++i)
#pragma unroll
    for (int j = 0; j < 4; ++j) acc[i][j] = (f32x4){0.f, 0.f, 0.f, 0.f};
  f16x8 af[4][2], bf[4][2];
  _Float16 r2h[8];

  const int rg4 = (l >> 4) * 4;  // C/D: col=lane&15, row=(lane>>4)*4+j

  // Prologue: tile0 fully + tile1 {Ah0,Bh0,Ah1}; wait until tile0 landed.
  STAGE_A(0, 0); STAGE_A(0, 1); STAGE_B(0, 0); STAGE_B(0, 1);
  STAGE_A(1, 0); STAGE_B(1, 0); STAGE_A(1, 1);
  WAITVM(6);
  BARRIER();

#pragma unroll 2
  for (int t = 0; t < NT; ++t) {
    const int bufo = (t & 1) * 16384;
    if constexpr (MODE == 2) {
      const int chb = (t & (TPS - 1)) * 256;  // K-chunk = t % TPS (BK=64=chunk)
#pragma unroll
      for (int i = 0; i < 8; ++i)
        r2h[i] = *(const _Float16*)&ldsR2[chb + wr128 + i * 16 + fr];
    }
    // ---- ph0: read A-half0 frags + B nf0..1; stage (t+1).Bh1
    RA8(0);
    RB4(0);
    if (t + 1 < NT) STAGE_B(t + 1, 1);
    BARRIER();
    __builtin_amdgcn_s_setprio(1); MFMA8(0, 0); __builtin_amdgcn_s_setprio(0);
    BARRIER();
    // ---- ph1: read B nf2..3; stage (t+2).Ah0
    RB4(2);
    if (t + 2 < NT) STAGE_A(t + 2, 0);
    BARRIER();
    __builtin_amdgcn_s_setprio(1); MFMA8(0, 2); __builtin_amdgcn_s_setprio(0);
    BARRIER();
    // ---- ph2: read A-half1 frags; stage (t+2).Bh0
    RA8(64);
    if (t + 2 < NT) STAGE_B(t + 2, 0);
    BARRIER();
    __builtin_amdgcn_s_setprio(1); MFMA8(4, 0); __builtin_amdgcn_s_setprio(0);
    BARRIER();
    // ---- ph3: stage (t+2).Ah1; counted vmcnt so next tile is resident
    if (t + 2 < NT) STAGE_A(t + 2, 1);
    BARRIER();
    __builtin_amdgcn_s_setprio(1); MFMA8(4, 2); __builtin_amdgcn_s_setprio(0);
    if (t + 2 < NT) { WAITVM(6); } else if (t + 1 < NT) { WAITVM(0); }
    BARRIER();

    // ---- M-tile boundary: per-wave epilogue (no cross-wave sync), acc reset.
    if ((t & (TPS - 1)) == (TPS - 1)) {
      const int m0c = m0base + (t / TPS) * 256;
      if constexpr (MODE == 1) {
        u16* Pc = Pout + (size_t)bz * ((size_t)2048 * 2048);
        const int chunk = (n0 >> 6) + wc;  // 64-col chunk id, 0..31
        const size_t tbase = ((size_t)bz * 32 + chunk) * 2048 + m0c;
#pragma unroll
        for (int mf = 0; mf < 8; ++mf) {
          float mt4[4], st4[4];
#pragma unroll
          for (int j = 0; j < 4; ++j) {
            const int r_ = wr128 + mf * 16 + rg4 + j;
            float v = fmaxf(fmaxf(acc[mf][0][j], acc[mf][1][j]),
                            fmaxf(acc[mf][2][j], acc[mf][3][j]));
#pragma unroll
            for (int off = 1; off < 16; off <<= 1) v = fmaxf(v, __shfl_xor(v, off, 64));
            const float e0 = __expf(acc[mf][0][j] - v);
            const float e1 = __expf(acc[mf][1][j] - v);
            const float e2 = __expf(acc[mf][2][j] - v);
            const float e3 = __expf(acc[mf][3][j] - v);
            u16* pr = Pc + (size_t)(m0c + r_) * 2048 + n0 + wc64 + cc;
            pr[0] = f2h(e0);
            pr[16] = f2h(e1);
            pr[32] = f2h(e2);
            pr[48] = f2h(e3);
            float s = (e0 + e1) + (e2 + e3);
#pragma unroll
            for (int off = 1; off < 16; off <<= 1) s += __shfl_xor(s, off, 64);
            mt4[j] = v;
            st4[j] = s;
          }
          if ((l & 15) == 0) {  // lanes 0,16,32,48 -> rows mf*16+rg4..+3
            const int r0 = wr128 + mf * 16 + rg4;
            *(float4*)&mtab[tbase + r0] = make_float4(mt4[0], mt4[1], mt4[2], mt4[3]);
            *(float4*)&stab[tbase + r0] = make_float4(st4[0], st4[1], st4[2], st4[3]);
          }
        }
      } else {
        // MODE 2: plain fp32 write (normalization already folded into r2')
#pragma unroll
        for (int mf = 0; mf < 8; ++mf)
#pragma unroll
          for (int nf = 0; nf < 4; ++nf) {
            float* cp = Fout + (size_t)bz * cBatch +
                        (size_t)(m0c + wr128 + mf * 16 + rg4) * N + n0 + wc64 + nf * 16 + cc;
#pragma unroll
            for (int j = 0; j < 4; ++j)
              cp[(size_t)j * N] = acc[mf][nf][j];
          }
      }
      if (t + 1 < NT) {
#pragma unroll
        for (int i = 0; i < 8; ++i)
#pragma unroll
          for (int j = 0; j < 4; ++j) acc[i][j] = (f32x4){0.f, 0.f, 0.f, 0.f};
      }
    }
  }
#undef STAGE_A
#undef STAGE_B
#undef RA8
#undef RB4
#undef MFMA8
}

// ---------------- aux kernels ----------------
__global__ __launch_bounds__(256) void k_conv_q(const float* __restrict__ in,
                                                u16* __restrict__ hi_o, int nrows) {
  int t = blockIdx.x * 256 + threadIdx.x;
  int total = nrows * (DD_ / 4);
  if (t >= total) return;
  int row = t >> 8;
  int c4 = (t & 255) << 2;
  float4 v = *(const float4*)(in + (size_t)row * DD_ + c4);
  u16x4 hi;
  hi.x = f2h(v.x);
  hi.y = f2h(v.y);
  hi.z = f2h(v.z);
  hi.w = f2h(v.w);
  *(u16x4*)(hi_o + (size_t)row * DD_ + c4) = hi;
}

__global__ __launch_bounds__(256) void k_conv_vt(const float* __restrict__ V,
                                                 u16* __restrict__ Vh,
                                                 u16* __restrict__ VT) {
  __shared__ u16 tile[64][65];
  const int d0 = blockIdx.x * 64, v0 = blockIdx.y * 64;
  const size_t boff = (size_t)blockIdx.z * LV_ * DD_;
  const float* Vb = V + boff;
  u16* Vhb = Vh + boff;
  u16* VTb = VT + (size_t)blockIdx.z * DD_ * LV_;
  const int t = threadIdx.x;
  const int r = t >> 4, c4 = (t & 15) * 4;
#pragma unroll
  for (int i = 0; i < 4; ++i) {
    int row = r + i * 16;
    float4 x = *(const float4*)(Vb + (size_t)(v0 + row) * DD_ + d0 + c4);
    u16x4 h;
    h.x = f2h(x.x);
    h.y = f2h(x.y);
    h.z = f2h(x.z);
    h.w = f2h(x.w);
    *(u16x4*)(Vhb + (size_t)(v0 + row) * DD_ + d0 + c4) = h;
    tile[row][c4 + 0] = h.x;
    tile[row][c4 + 1] = h.y;
    tile[row][c4 + 2] = h.z;
    tile[row][c4 + 3] = h.w;
  }
  __syncthreads();
#pragma unroll
  for (int i = 0; i < 4; ++i) {
    int row = r + i * 16;
    u16x4 o;
    o.x = tile[c4 + 0][row];
    o.y = tile[c4 + 1][row];
    o.z = tile[c4 + 2][row];
    o.w = tile[c4 + 3][row];
    *(u16x4*)(VTb + (size_t)(d0 + row) * LV_ + v0 + c4) = o;
  }
}

extern "C" void kernel_launch(void* const* d_in, const int* in_sizes, int n_in,
                              void* d_out, int out_size, void* d_ws, size_t ws_size,
                              hipStream_t stream) {
  const float* Q = (const float*)d_in[0];
  const float* V = (const float*)d_in[1];
  float* out = (float*)d_out;

  const size_t qv_e = (size_t)LQ_ * DD_;      // 2M elems
  const size_t vt_e = (size_t)DD_ * LV_;      // 2M
  const size_t p_e = (size_t)LQ_ * LV_;       // 4M
  const size_t tab_e = (size_t)32 * 2048;     // per-batch table entries
  const size_t per_batch =
      qv_e * 2 * 2 + vt_e * 2 + p_e * 2 + tab_e * 4 * 2;

  int nb = (int)(ws_size / per_batch);
  if (nb < 1) nb = 1;
  if (nb > B_) nb = B_;

  char* wp = (char*)d_ws;
  u16* Qh = (u16*)wp;    wp += (size_t)nb * qv_e * 2;
  u16* Vh = (u16*)wp;    wp += (size_t)nb * qv_e * 2;
  u16* VT = (u16*)wp;    wp += (size_t)nb * vt_e * 2;
  u16* P = (u16*)wp;     wp += (size_t)nb * p_e * 2;
  float* mtab = (float*)wp;  wp += (size_t)nb * tab_e * 4;
  float* stab = (float*)wp;

  for (int b0 = 0; b0 < B_; b0 += nb) {
    const int cb = (nb < B_ - b0) ? nb : (B_ - b0);
    const int rows = cb * LQ_;
    const int cthreads = rows * (DD_ / 4);
    k_conv_q<<<dim3((cthreads + 255) / 256), dim3(256), 0, stream>>>(
        Q + (size_t)b0 * LQ_ * DD_, Qh, rows);
    k_conv_vt<<<dim3(DD_ / 64, LV_ / 64, cb), dim3(256), 0, stream>>>(
        V + (size_t)b0 * LV_ * DD_, Vh, VT);
    // GEMM1 + per-wave-chunk softmax stats: 2 M-tiles/block (B panel L2-hot)
    k_gemm8<2, 16, 1><<<dim3(LV_ / 256, LQ_ / 512, cb), dim3(512), 0, stream>>>(
        Qh, Vh, P, nullptr, mtab, stab,
        LV_, DD_, DD_, qv_e, qv_e, 0);
    // GEMM2 (stats folded into prologue): out = sum_c (P_c * r2'[c]) . VT_c^T
    k_gemm8<1, 32, 2><<<dim3(DD_ / 256, LQ_ / 256, cb), dim3(512), 0, stream>>>(
        P, VT, nullptr, out + (size_t)b0 * LQ_ * DD_, mtab, stab,
        DD_, LV_, LV_, p_e, vt_e, (size_t)LQ_ * DD_);
  }
}

// Round 14
// 416.072 us; speedup vs baseline: 1.2504x; 1.2504x over previous
//
#include <hip/hip_runtime.h>

// softmax(Q.V^T).V — deferred-normalization pipeline (fp16):
//   conv:  Q -> Qh fp16;  V -> Vh fp16 + VT (=Vh^T)
//   GEMM1f (MODE 1): S-tile = Qh.Vh^T (proven 8-phase 256²); per-wave epilogue:
//       per 64-col chunk c: m_c[r] = chunk row-max (16-lane shfl only),
//       P_c = fp16(exp(S - m_c)), s_c[r] = chunk row-sum. No cross-wave sync.
//   k_stats: per row: m_g = max_c m_c; denom = sum_c s_c*exp(m_c-m_g);
//       r2'[c] = exp(m_c - m_g)/denom  (fin folded in, fp16).
//   GEMM2 (MODE 2): out = sum_t (P_t * r2'[t]) . VT_t^T   (exact softmax.V)
// GEMM geometry (proven): 256² tile, BK=64, 8 waves (2x4), 8-phase,
// counted vmcnt(6), XOR-swizzle via pre-swizzled global source, XCD remap.
// NOTE (R13 lesson): epilogue stores must stay AFTER the K-loop — global_store
// increments vmcnt, so in-loop epilogues poison the counted-vmcnt schedule.

#define B_ 16
#define LQ_ 2048
#define LV_ 2048
#define DD_ 1024

typedef unsigned short u16;
typedef _Float16 f16x8 __attribute__((ext_vector_type(8)));
typedef __attribute__((ext_vector_type(4))) float f32x4;
typedef __attribute__((ext_vector_type(4))) unsigned short u16x4;

__device__ __forceinline__ u16 f2h(float x) {
  union { _Float16 h; u16 u; } c;
  c.h = (_Float16)x;
  return c.u;
}

__device__ __forceinline__ void gload16(const u16* g, u16* lds) {
  __builtin_amdgcn_global_load_lds(
      (const __attribute__((address_space(1))) void*)g,
      (__attribute__((address_space(3))) void*)lds, 16, 0, 0);
}

#define BARRIER() do { asm volatile("" ::: "memory"); __builtin_amdgcn_s_barrier(); asm volatile("" ::: "memory"); } while (0)
#define WAITVM(N) asm volatile("s_waitcnt vmcnt(" #N ")" ::: "memory")

// ---------------- 256x256 8-phase GEMM ----------------
// MODE 1: A.B^T -> P=exp(S-m_chunk) fp16 + per-64-col-chunk m/s tables
// MODE 2: sum_t (A_t*r2'[t]).B_t^T -> fp32 (deferred normalization)
template <int TPS, int MODE>
__global__ __launch_bounds__(512, 2) void k_gemm8(
    const u16* __restrict__ A, const u16* __restrict__ B,
    u16* __restrict__ Pout, float* __restrict__ Fout,
    const u16* __restrict__ r2tab,
    float* __restrict__ mtab, float* __restrict__ stab,
    int N, int lda, int ldb, size_t aBatch, size_t bBatch, size_t cBatch) {
  constexpr int NT = TPS;
  __shared__ u16 lds[65536];  // A: 2 bufs x 256x64 | B: 2 bufs x 256x64
  __shared__ u16 ldsR2[(MODE == 2) ? 8192 : 64];  // [32 chunks][256 rows]
  u16* ldsA = lds;
  u16* ldsB = lds + 32768;

  // XCD-aware bijective remap (nwg % 8 == 0)
  int bx, by, bz;
  {
    const int gx = gridDim.x, gy = gridDim.y;
    const int lid = blockIdx.x + gx * (blockIdx.y + gy * blockIdx.z);
    const int nwg = gx * gy * gridDim.z;
    const int q = nwg >> 3;
    const int nid = (lid & 7) * q + (lid >> 3);
    bx = nid % gx;
    const int rem = nid / gx;
    by = rem % gy;
    bz = rem / gy;
  }

  const int tid = threadIdx.x;
  const int w = tid >> 6, l = tid & 63;
  const int m0 = by << 8, n0 = bx << 8;
  const int wr = w >> 2, wc = w & 3;  // 2(M) x 4(N) waves -> 128x64 per wave
  const int wr128 = wr * 128, wc64 = wc * 64;
  const int fr = l & 15, kx = l >> 4, fr7 = l & 7, cc = l & 15;
  const int srow = l >> 3;
  const int gsrc8 = (((l & 7) ^ ((l >> 3) & 7)) << 3);  // inverse-swizzled src granule

  const u16* Ab = A + (size_t)bz * aBatch;
  const u16* Bb = B + (size_t)bz * bBatch;

  if constexpr (MODE == 2) {
    for (int i = tid; i < 8192; i += 512)
      ldsR2[i] = r2tab[((size_t)bz * 32 + (i >> 8)) * 2048 + m0 + (i & 255)];
    __syncthreads();
  }

  // A half h covers tile rows {h*64..h*64+63} u {128+h*64..+63}
#define STAGE_A(tt, h)                                                          \
  do {                                                                          \
    const int kk_ = (tt) * 64;                                                  \
    u16* d0_ = ldsA + ((tt) & 1) * 16384 + ((h) * 64 + w * 8) * 64;             \
    const u16* g0_ = Ab + (size_t)(m0 + (h) * 64 + w * 8 + srow) * lda + kk_ + gsrc8; \
    gload16(g0_, d0_);                                                          \
    gload16(g0_ + (size_t)128 * lda, d0_ + 128 * 64);                           \
  } while (0)

  // B half h covers tile rows { k*64 + h*32 .. +31 : k=0..3 }
#define STAGE_B(tt, h)                                                          \
  do {                                                                          \
    const int kk_ = (tt) * 64;                                                  \
    const int rb_ = (w >> 2) * 64 + (h) * 32 + (w & 3) * 8;                     \
    u16* d0_ = ldsB + ((tt) & 1) * 16384 + rb_ * 64;                            \
    const u16* g0_ = Bb + (size_t)(n0 + rb_ + srow) * ldb + kk_ + gsrc8;        \
    gload16(g0_, d0_);                                                          \
    gload16(g0_ + (size_t)128 * ldb, d0_ + 8192);                               \
  } while (0)

#define RA8(MOFF)                                                                   \
  {                                                                                 \
    _Pragma("unroll") for (int m_ = 0; m_ < 4; ++m_) {                              \
      _Pragma("unroll") for (int k_ = 0; k_ < 2; ++k_) {                            \
        af[m_][k_] = *(const f16x8*)(ldsA + bufo +                                  \
            (wr128 + (MOFF) + m_ * 16 + fr) * 64 + (((kx + k_ * 4) ^ fr7) << 3));   \
        if constexpr (MODE == 2) af[m_][k_] = af[m_][k_] * r2h[(MOFF) / 16 + m_];   \
      }                                                                             \
    }                                                                               \
  }

#define RB4(NF0)                                                                    \
  {                                                                                 \
    _Pragma("unroll") for (int n_ = 0; n_ < 2; ++n_) {                              \
      _Pragma("unroll") for (int k_ = 0; k_ < 2; ++k_) {                            \
        bf[(NF0) + n_][k_] = *(const f16x8*)(ldsB + bufo +                          \
            (wc64 + ((NF0) + n_) * 16 + fr) * 64 + (((kx + k_ * 4) ^ fr7) << 3));   \
      }                                                                             \
    }                                                                               \
  }

#define MFMA8(MF0, NF0)                                                             \
  {                                                                                 \
    _Pragma("unroll") for (int m_ = 0; m_ < 4; ++m_)                                \
    _Pragma("unroll") for (int n_ = 0; n_ < 2; ++n_)                                \
    _Pragma("unroll") for (int k_ = 0; k_ < 2; ++k_)                                \
        acc[(MF0) + m_][(NF0) + n_] = __builtin_amdgcn_mfma_f32_16x16x32_f16(       \
            af[m_][k_], bf[(NF0) + n_][k_], acc[(MF0) + m_][(NF0) + n_], 0, 0, 0);  \
  }

  f32x4 acc[8][4];
#pragma unroll
  for (int i = 0; i < 8; ++i)
#pragma unroll
    for (int j = 0; j < 4; ++j) acc[i][j] = (f32x4){0.f, 0.f, 0.f, 0.f};
  f16x8 af[4][2], bf[4][2];
  _Float16 r2h[8];

  // Prologue: tile0 fully + tile1 {Ah0,Bh0,Ah1}; wait until tile0 landed.
  STAGE_A(0, 0); STAGE_A(0, 1); STAGE_B(0, 0); STAGE_B(0, 1);
  STAGE_A(1, 0); STAGE_B(1, 0); STAGE_A(1, 1);
  WAITVM(6);
  BARRIER();

#pragma unroll 2
  for (int t = 0; t < NT; ++t) {
    const int bufo = (t & 1) * 16384;
    if constexpr (MODE == 2) {
#pragma unroll
      for (int i = 0; i < 8; ++i)
        r2h[i] = *(const _Float16*)&ldsR2[t * 256 + wr128 + i * 16 + fr];
    }
    // ---- ph0: read A-half0 frags + B nf0..1; stage (t+1).Bh1
    RA8(0);
    RB4(0);
    if (t + 1 < NT) STAGE_B(t + 1, 1);
    BARRIER();
    __builtin_amdgcn_s_setprio(1); MFMA8(0, 0); __builtin_amdgcn_s_setprio(0);
    BARRIER();
    // ---- ph1: read B nf2..3; stage (t+2).Ah0
    RB4(2);
    if (t + 2 < NT) STAGE_A(t + 2, 0);
    BARRIER();
    __builtin_amdgcn_s_setprio(1); MFMA8(0, 2); __builtin_amdgcn_s_setprio(0);
    BARRIER();
    // ---- ph2: read A-half1 frags; stage (t+2).Bh0
    RA8(64);
    if (t + 2 < NT) STAGE_B(t + 2, 0);
    BARRIER();
    __builtin_amdgcn_s_setprio(1); MFMA8(4, 0); __builtin_amdgcn_s_setprio(0);
    BARRIER();
    // ---- ph3: stage (t+2).Ah1; counted vmcnt so next tile is resident
    if (t + 2 < NT) STAGE_A(t + 2, 1);
    BARRIER();
    __builtin_amdgcn_s_setprio(1); MFMA8(4, 2); __builtin_amdgcn_s_setprio(0);
    if (t + 2 < NT) { WAITVM(6); } else if (t + 1 < NT) { WAITVM(0); }
    BARRIER();
  }

  const int rg4 = (l >> 4) * 4;  // C/D: col=lane&15, row=(lane>>4)*4+j
  if constexpr (MODE == 1) {
    // --- per-wave fused softmax epilogue (64-col chunk per wave-column) ---
    u16* Pc = Pout + (size_t)bz * ((size_t)2048 * 2048);
    const int chunk = bx * 4 + wc;  // 0..31
    const size_t tbase = ((size_t)bz * 32 + chunk) * 2048 + m0;
#pragma unroll
    for (int mf = 0; mf < 8; ++mf) {
      float mt4[4], st4[4];
#pragma unroll
      for (int j = 0; j < 4; ++j) {
        const int r_ = wr128 + mf * 16 + rg4 + j;
        float v = fmaxf(fmaxf(acc[mf][0][j], acc[mf][1][j]),
                        fmaxf(acc[mf][2][j], acc[mf][3][j]));
#pragma unroll
        for (int off = 1; off < 16; off <<= 1) v = fmaxf(v, __shfl_xor(v, off, 64));
        const float e0 = __expf(acc[mf][0][j] - v);
        const float e1 = __expf(acc[mf][1][j] - v);
        const float e2 = __expf(acc[mf][2][j] - v);
        const float e3 = __expf(acc[mf][3][j] - v);
        u16* pr = Pc + (size_t)(m0 + r_) * 2048 + n0 + wc64 + cc;
        pr[0] = f2h(e0);
        pr[16] = f2h(e1);
        pr[32] = f2h(e2);
        pr[48] = f2h(e3);
        float s = (e0 + e1) + (e2 + e3);
#pragma unroll
        for (int off = 1; off < 16; off <<= 1) s += __shfl_xor(s, off, 64);
        mt4[j] = v;
        st4[j] = s;
      }
      if ((l & 15) == 0) {  // lanes 0,16,32,48 -> rows mf*16+rg4..+3
        const int r0 = wr128 + mf * 16 + rg4;
        *(float4*)&mtab[tbase + r0] = make_float4(mt4[0], mt4[1], mt4[2], mt4[3]);
        *(float4*)&stab[tbase + r0] = make_float4(st4[0], st4[1], st4[2], st4[3]);
      }
    }
  } else {
    // --- MODE 2: plain fp32 write (normalization already folded into r2') ---
#pragma unroll
    for (int mf = 0; mf < 8; ++mf)
#pragma unroll
      for (int nf = 0; nf < 4; ++nf) {
        float* cp = Fout + (size_t)bz * cBatch +
                    (size_t)(m0 + wr128 + mf * 16 + rg4) * N + n0 + wc64 + nf * 16 + cc;
#pragma unroll
        for (int j = 0; j < 4; ++j)
          cp[(size_t)j * N] = acc[mf][nf][j];
      }
  }
#undef STAGE_A
#undef STAGE_B
#undef RA8
#undef RB4
#undef MFMA8
}

// ---------------- stats kernel: per-row fold normalization into r2' ---------
__global__ __launch_bounds__(256) void k_stats(const float* __restrict__ mtab,
                                               const float* __restrict__ stab,
                                               u16* __restrict__ r2tab) {
  const int r = blockIdx.x * 256 + threadIdx.x;  // 0..2047
  const int bz = blockIdx.y;
  float m[32], s[32], mg = -3.0e38f;
#pragma unroll
  for (int t = 0; t < 32; ++t) {
    m[t] = mtab[((size_t)bz * 32 + t) * 2048 + r];
    s[t] = stab[((size_t)bz * 32 + t) * 2048 + r];
    mg = fmaxf(mg, m[t]);
  }
  float denom = 0.f;
  float f[32];
#pragma unroll
  for (int t = 0; t < 32; ++t) {
    f[t] = __expf(m[t] - mg);
    denom += s[t] * f[t];
  }
  const float inv = 1.0f / denom;
#pragma unroll
  for (int t = 0; t < 32; ++t)
    r2tab[((size_t)bz * 32 + t) * 2048 + r] = f2h(f[t] * inv);
}

// ---------------- aux kernels ----------------
__global__ __launch_bounds__(256) void k_conv_q(const float* __restrict__ in,
                                                u16* __restrict__ hi_o, int nrows) {
  int t = blockIdx.x * 256 + threadIdx.x;
  int total = nrows * (DD_ / 4);
  if (t >= total) return;
  int row = t >> 8;
  int c4 = (t & 255) << 2;
  float4 v = *(const float4*)(in + (size_t)row * DD_ + c4);
  u16x4 hi;
  hi.x = f2h(v.x);
  hi.y = f2h(v.y);
  hi.z = f2h(v.z);
  hi.w = f2h(v.w);
  *(u16x4*)(hi_o + (size_t)row * DD_ + c4) = hi;
}

__global__ __launch_bounds__(256) void k_conv_vt(const float* __restrict__ V,
                                                 u16* __restrict__ Vh,
                                                 u16* __restrict__ VT) {
  __shared__ u16 tile[64][65];
  const int d0 = blockIdx.x * 64, v0 = blockIdx.y * 64;
  const size_t boff = (size_t)blockIdx.z * LV_ * DD_;
  const float* Vb = V + boff;
  u16* Vhb = Vh + boff;
  u16* VTb = VT + (size_t)blockIdx.z * DD_ * LV_;
  const int t = threadIdx.x;
  const int r = t >> 4, c4 = (t & 15) * 4;
#pragma unroll
  for (int i = 0; i < 4; ++i) {
    int row = r + i * 16;
    float4 x = *(const float4*)(Vb + (size_t)(v0 + row) * DD_ + d0 + c4);
    u16x4 h;
    h.x = f2h(x.x);
    h.y = f2h(x.y);
    h.z = f2h(x.z);
    h.w = f2h(x.w);
    *(u16x4*)(Vhb + (size_t)(v0 + row) * DD_ + d0 + c4) = h;
    tile[row][c4 + 0] = h.x;
    tile[row][c4 + 1] = h.y;
    tile[row][c4 + 2] = h.z;
    tile[row][c4 + 3] = h.w;
  }
  __syncthreads();
#pragma unroll
  for (int i = 0; i < 4; ++i) {
    int row = r + i * 16;
    u16x4 o;
    o.x = tile[c4 + 0][row];
    o.y = tile[c4 + 1][row];
    o.z = tile[c4 + 2][row];
    o.w = tile[c4 + 3][row];
    *(u16x4*)(VTb + (size_t)(d0 + row) * LV_ + v0 + c4) = o;
  }
}

extern "C" void kernel_launch(void* const* d_in, const int* in_sizes, int n_in,
                              void* d_out, int out_size, void* d_ws, size_t ws_size,
                              hipStream_t stream) {
  const float* Q = (const float*)d_in[0];
  const float* V = (const float*)d_in[1];
  float* out = (float*)d_out;

  const size_t qv_e = (size_t)LQ_ * DD_;      // 2M elems
  const size_t vt_e = (size_t)DD_ * LV_;      // 2M
  const size_t p_e = (size_t)LQ_ * LV_;       // 4M
  const size_t tab_e = (size_t)32 * 2048;     // per-batch table entries
  const size_t per_batch =
      qv_e * 2 * 2 + vt_e * 2 + p_e * 2 + tab_e * 4 * 2 + tab_e * 2;

  int nb = (int)(ws_size / per_batch);
  if (nb < 1) nb = 1;
  if (nb > B_) nb = B_;

  char* wp = (char*)d_ws;
  u16* Qh = (u16*)wp;    wp += (size_t)nb * qv_e * 2;
  u16* Vh = (u16*)wp;    wp += (size_t)nb * qv_e * 2;
  u16* VT = (u16*)wp;    wp += (size_t)nb * vt_e * 2;
  u16* P = (u16*)wp;     wp += (size_t)nb * p_e * 2;
  float* mtab = (float*)wp;  wp += (size_t)nb * tab_e * 4;
  float* stab = (float*)wp;  wp += (size_t)nb * tab_e * 4;
  u16* r2tab = (u16*)wp;

  for (int b0 = 0; b0 < B_; b0 += nb) {
    const int cb = (nb < B_ - b0) ? nb : (B_ - b0);
    const int rows = cb * LQ_;
    const int cthreads = rows * (DD_ / 4);
    k_conv_q<<<dim3((cthreads + 255) / 256), dim3(256), 0, stream>>>(
        Q + (size_t)b0 * LQ_ * DD_, Qh, rows);
    k_conv_vt<<<dim3(DD_ / 64, LV_ / 64, cb), dim3(256), 0, stream>>>(
        V + (size_t)b0 * LV_ * DD_, Vh, VT);
    // GEMM1 + per-wave-chunk softmax stats -> P = exp(S - m_chunk), m/s tables
    k_gemm8<16, 1><<<dim3(LV_ / 256, LQ_ / 256, cb), dim3(512), 0, stream>>>(
        Qh, Vh, P, nullptr, nullptr, mtab, stab,
        LV_, DD_, DD_, qv_e, qv_e, 0);
    k_stats<<<dim3(LQ_ / 256, cb), dim3(256), 0, stream>>>(mtab, stab, r2tab);
    // GEMM2: out = sum_t (P_t * r2'[t]) . VT_t^T
    k_gemm8<32, 2><<<dim3(DD_ / 256, LQ_ / 256, cb), dim3(512), 0, stream>>>(
        P, VT, nullptr, out + (size_t)b0 * LQ_ * DD_, r2tab, nullptr, nullptr,
        DD_, LV_, LV_, p_e, vt_e, (size_t)LQ_ * DD_);
  }
}